// Round 1
// baseline (3586.577 us; speedup 1.0000x reference)
//
#include <hip/hip_runtime.h>

#define Hdim 224
#define HW   50176      // 224*224
#define KCUT 56
#define CHUNK 128       // slices per chunk
#define NCHUNK 12
#define ROWS  (CHUNK*Hdim)   // 28672 GEMM rows per chunk
#define BK 16
#define BM 128
#define BN 112

// ws float offsets
#define OFF_D 0
#define OFF_M 50176
#define OFF_P 100352
#define OFF_R 150528
#define OFF_Y (OFF_R + ROWS*Hdim)   // 150528 + 6422528 = 6573056
// total ws floats: 6573056 + 6422528 = 12995584 -> ~49.6 MB

#define DPI 3.14159265358979323846

__global__ void k_build_D(float* __restrict__ D) {
    int idx = blockIdx.x * 256 + threadIdx.x;
    if (idx >= HW) return;
    int k = idx / Hdim, i = idx - k * Hdim;
    double v = cos(DPI * (2.0 * i + 1.0) * (double)k / (2.0 * Hdim)) * sqrt(2.0 / Hdim);
    if (k == 0) v *= 0.70710678118654752440;
    D[idx] = (float)v;
}

__global__ void k_build_MP(const float* __restrict__ D,
                           float* __restrict__ M, float* __restrict__ P) {
    int idx = blockIdx.x * 256 + threadIdx.x;
    if (idx >= HW) return;
    int i = idx / Hdim, j = idx - i * Hdim;
    float m = 0.f, p = 0.f;
    for (int k = 0; k < Hdim; ++k) {
        float t = D[i * Hdim + k] * D[k * Hdim + j];
        m += t;
        if (k < KCUT) p += t;
    }
    M[idx] = m;
    P[idx] = p;
}

// Generic BT-GEMM over a chunk: C[row, n] = sum_k A[row*224+k] * B[n*224+k]
// MODE 0: per-slice transposed write into R:  R[s*HW + n*224 + h]   (row = s*224+h)
// MODE 1: plain write into Y:                 Y[row*224 + n]
// MODE 2: fused epilogue: out = x * (Y - z):  row = (s,j), n = i
template<int MODE>
__global__ __launch_bounds__(256)
void k_gemm(const float* __restrict__ A,   // ROWS x 224 flat
            const float* __restrict__ B,   // 224 x 224 (B^T form: B[n,k])
            float* __restrict__ Cout,
            const float* __restrict__ Yb,  // MODE2: Y buffer
            const float* __restrict__ Xc)  // MODE2: x chunk
{
    __shared__ float As[BK][132];   // padded stride vs 128: break bank conflicts
    __shared__ float Bs[BK][116];   // padded vs 112
    const int t = threadIdx.x;
    const int m0 = blockIdx.y * BM;
    const int n0 = blockIdx.x * BN;

    float acc[8][8];
    #pragma unroll
    for (int a = 0; a < 8; ++a)
        #pragma unroll
        for (int b = 0; b < 8; ++b) acc[a][b] = 0.f;

    const int ty = t / 14;          // 16 row-groups
    const int tx = t - ty * 14;     // 14 col-groups (t<224 active for compute)

    for (int k0 = 0; k0 < Hdim; k0 += BK) {
        // stage A tile: BM x BK = 512 float4
        #pragma unroll
        for (int e = t; e < (BM * BK) / 4; e += 256) {
            int m = e >> 2, kk4 = (e & 3) << 2;
            const float4 v = *(const float4*)(A + (size_t)(m0 + m) * Hdim + k0 + kk4);
            As[kk4 + 0][m] = v.x; As[kk4 + 1][m] = v.y;
            As[kk4 + 2][m] = v.z; As[kk4 + 3][m] = v.w;
        }
        // stage B tile: BN x BK = 448 float4
        for (int e = t; e < (BN * BK) / 4; e += 256) {
            int n = e >> 2, kk4 = (e & 3) << 2;
            const float4 v = *(const float4*)(B + (size_t)(n0 + n) * Hdim + k0 + kk4);
            Bs[kk4 + 0][n] = v.x; Bs[kk4 + 1][n] = v.y;
            Bs[kk4 + 2][n] = v.z; Bs[kk4 + 3][n] = v.w;
        }
        __syncthreads();
        if (t < 224) {
            const int mt = ty * 8, nt = tx * 8;
            #pragma unroll
            for (int kk = 0; kk < BK; ++kk) {
                float a[8], b[8];
                *(float4*)&a[0] = *(const float4*)&As[kk][mt];
                *(float4*)&a[4] = *(const float4*)&As[kk][mt + 4];
                *(float4*)&b[0] = *(const float4*)&Bs[kk][nt];
                *(float4*)&b[4] = *(const float4*)&Bs[kk][nt + 4];
                #pragma unroll
                for (int rr = 0; rr < 8; ++rr)
                    #pragma unroll
                    for (int cc = 0; cc < 8; ++cc)
                        acc[rr][cc] += a[rr] * b[cc];
            }
        }
        __syncthreads();
    }

    if (t >= 224) return;
    const int mt = m0 + ty * 8, nt = n0 + tx * 8;
    #pragma unroll
    for (int rr = 0; rr < 8; ++rr) {
        const int r = mt + rr;                 // GEMM row
        const int s = r / Hdim;                // slice within chunk
        const int h = r - s * Hdim;            // h (MODE0) or j (MODE2)
        #pragma unroll
        for (int cc = 0; cc < 8; ++cc) {
            const int c = nt + cc;             // GEMM col
            if (MODE == 0) {
                Cout[(size_t)s * HW + (size_t)c * Hdim + h] = acc[rr][cc];
            } else if (MODE == 1) {
                Cout[(size_t)r * Hdim + c] = acc[rr][cc];
            } else {
                // row=(s,j=h), col=i=c: z = acc, y = Yb[row, i]
                const float yv = Yb[(size_t)r * Hdim + c];
                const size_t xo = (size_t)s * HW + (size_t)c * Hdim + h;
                const float xv = Xc[xo];
                Cout[xo] = xv * (yv - acc[rr][cc]);
            }
        }
    }
}

extern "C" void kernel_launch(void* const* d_in, const int* in_sizes, int n_in,
                              void* d_out, int out_size, void* d_ws, size_t ws_size,
                              hipStream_t stream) {
    const float* x = (const float*)d_in[0];
    float* out = (float*)d_out;
    float* w = (float*)d_ws;
    float* D = w + OFF_D;
    float* M = w + OFF_M;
    float* P = w + OFF_P;
    float* R = w + OFF_R;
    float* Y = w + OFF_Y;

    k_build_D<<<dim3((HW + 255) / 256), dim3(256), 0, stream>>>(D);
    k_build_MP<<<dim3((HW + 255) / 256), dim3(256), 0, stream>>>(D, M, P);

    dim3 grid(Hdim / BN, ROWS / BM);   // (2, 224)
    dim3 blk(256);
    for (int c = 0; c < NCHUNK; ++c) {
        const float* xc = x + (size_t)c * CHUNK * HW;
        float* oc = out + (size_t)c * CHUNK * HW;
        // M-chain: R = per-slice-transposed(x @ M^T); Y = (M x M^T)^T rows
        k_gemm<0><<<grid, blk, 0, stream>>>(xc, M, R, nullptr, nullptr);
        k_gemm<1><<<grid, blk, 0, stream>>>(R, M, Y, nullptr, nullptr);
        // P-chain reuses R; final pass fuses z, y-read, x-mul, out-write
        k_gemm<0><<<grid, blk, 0, stream>>>(xc, P, R, nullptr, nullptr);
        k_gemm<2><<<grid, blk, 0, stream>>>(R, P, oc, Y, xc);
    }
}

// Round 2
// 1024.908 us; speedup vs baseline: 3.4994x; 3.4994x over previous
//
#include <hip/hip_runtime.h>
#include <hip/hip_bf16.h>

#define Hdim 224
#define HW   50176        // 224*224
#define KCUT 56
#define CHUNK 128         // slices per chunk
#define NCHUNK 12
#define ROWS  (CHUNK*Hdim)   // 28672 GEMM rows per chunk
#define BK 32
#define BM 128
#define BN 112

// ws float offsets
#define OFF_D  0
#define OFF_M  50176                 // bf16 M, 50176 el = 25088 floats
#define OFF_P  (OFF_M + 25088)
#define OFF_RM (OFF_P + 25088)       // bf16, CHUNK*HW el = 3211264 floats
#define OFF_RP (OFF_RM + 3211264)
// total = 50176 + 2*25088 + 2*3211264 floats ~= 26.1 MB  (< 49.6 MB proven in R1)

#define DPI 3.14159265358979323846

typedef __attribute__((ext_vector_type(8))) short short8;   // 8 bf16 = 4 VGPR
typedef __attribute__((ext_vector_type(4))) float f32x4;

__device__ __forceinline__ void gl_lds16(const void* g, void* l) {
    __builtin_amdgcn_global_load_lds(
        (__attribute__((address_space(1))) const void*)g,
        (__attribute__((address_space(3))) void*)l, 16, 0, 0);
}

__device__ __forceinline__ f32x4 mfma_bf16(short8 a, short8 b, f32x4 c) {
    return __builtin_amdgcn_mfma_f32_16x16x32_bf16(a, b, c, 0, 0, 0);
}

__global__ void k_build_D(float* __restrict__ D) {
    int idx = blockIdx.x * 256 + threadIdx.x;
    if (idx >= HW) return;
    int k = idx / Hdim, i = idx - k * Hdim;
    double v = cos(DPI * (2.0 * i + 1.0) * (double)k / (2.0 * Hdim)) * sqrt(2.0 / Hdim);
    if (k == 0) v *= 0.70710678118654752440;
    D[idx] = (float)v;
}

__global__ void k_build_MP(const float* __restrict__ D,
                           __hip_bfloat16* __restrict__ Mb,
                           __hip_bfloat16* __restrict__ Pb) {
    int idx = blockIdx.x * 256 + threadIdx.x;
    if (idx >= HW) return;
    int i = idx / Hdim, j = idx - i * Hdim;
    float m = 0.f, p = 0.f;
    for (int k = 0; k < Hdim; ++k) {
        float t = D[i * Hdim + k] * D[k * Hdim + j];
        m += t;
        if (k < KCUT) p += t;
    }
    Mb[idx] = __float2bfloat16(m);
    Pb[idx] = __float2bfloat16(p);
}

// Pass 1: dual BT-GEMM sharing the A tile (x fp32, cvt at staging).
//   RM[s, a, h] = sum_t x[s,h,t] * M[a,t]   (per-slice transposed write)
//   RP[s, a, h] = sum_t x[s,h,t] * P[a,t]
__global__ __launch_bounds__(256, 2)
void k_pass1(const float* __restrict__ X,
             const __hip_bfloat16* __restrict__ Mb,
             const __hip_bfloat16* __restrict__ Pb,
             __hip_bfloat16* __restrict__ RM,
             __hip_bfloat16* __restrict__ RP)
{
    __shared__ __hip_bfloat16 As[BM * BK];    // [row][32k] 64B rows
    __shared__ __hip_bfloat16 B1s[BN * BK];
    __shared__ __hip_bfloat16 B2s[BN * BK];
    const int t = threadIdx.x;
    const int l = t & 63, wv = t >> 6;
    const int m0 = blockIdx.y * BM, n0 = blockIdx.x * BN;
    const int col = l & 15, q = l >> 4;

    f32x4 accM[2][7], accP[2][7];
    #pragma unroll
    for (int i = 0; i < 2; ++i)
        #pragma unroll
        for (int j = 0; j < 7; ++j) { accM[i][j] = (f32x4)0.f; accP[i][j] = (f32x4)0.f; }

    for (int k0 = 0; k0 < Hdim; k0 += BK) {
        if (k0) __syncthreads();
        // A: fp32 -> bf16 manual staging (1024 float4 groups, 4 per thread)
        #pragma unroll
        for (int e = t; e < (BM * BK) / 4; e += 256) {
            int row = e >> 3, c4 = (e & 7) * 4;
            const float4 v = *(const float4*)(X + (size_t)(m0 + row) * Hdim + k0 + c4);
            __hip_bfloat16 tmp[4];
            tmp[0] = __float2bfloat16(v.x); tmp[1] = __float2bfloat16(v.y);
            tmp[2] = __float2bfloat16(v.z); tmp[3] = __float2bfloat16(v.w);
            *(uint2*)(&As[row * BK + c4]) = *(uint2*)tmp;
        }
        // B tiles: async 16B/lane, 16 rows (1 KiB) per instruction, wave round-robin
        for (int i = wv; i < 7; i += 4) {
            int r0 = i * 16;
            gl_lds16(Mb + (size_t)(n0 + r0 + (l >> 2)) * Hdim + k0 + (l & 3) * 8,
                     &B1s[r0 * BK]);
            gl_lds16(Pb + (size_t)(n0 + r0 + (l >> 2)) * Hdim + k0 + (l & 3) * 8,
                     &B2s[r0 * BK]);
        }
        __syncthreads();
        const short8 a0 = *(const short8*)(&As[(wv * 32 + col) * BK + q * 8]);
        const short8 a1 = *(const short8*)(&As[(wv * 32 + 16 + col) * BK + q * 8]);
        #pragma unroll
        for (int j = 0; j < 7; ++j) {
            const short8 b1 = *(const short8*)(&B1s[(j * 16 + col) * BK + q * 8]);
            const short8 b2 = *(const short8*)(&B2s[(j * 16 + col) * BK + q * 8]);
            accM[0][j] = mfma_bf16(a0, b1, accM[0][j]);
            accM[1][j] = mfma_bf16(a1, b1, accM[1][j]);
            accP[0][j] = mfma_bf16(a0, b2, accP[0][j]);
            accP[1][j] = mfma_bf16(a1, b2, accP[1][j]);
        }
    }

    // epilogue: per-slice transposed bf16 write; 4 acc rows are 4 consecutive h
    #pragma unroll
    for (int i = 0; i < 2; ++i) {
        const int r0 = m0 + wv * 32 + i * 16 + q * 4;  // never straddles slice (mult of 4)
        const int s = r0 / Hdim, h = r0 - (r0 / Hdim) * Hdim;
        #pragma unroll
        for (int j = 0; j < 7; ++j) {
            const int a = n0 + j * 16 + col;
            const size_t off = (size_t)s * HW + (size_t)a * Hdim + h;
            __hip_bfloat16 tm[4], tp[4];
            #pragma unroll
            for (int r = 0; r < 4; ++r) {
                tm[r] = __float2bfloat16(accM[i][j][r]);
                tp[r] = __float2bfloat16(accP[i][j][r]);
            }
            *(uint2*)(RM + off) = *(uint2*)tm;
            *(uint2*)(RP + off) = *(uint2*)tp;
        }
    }
}

// Pass 2: dual BT-GEMM (independent A's) + fused epilogue out = x * (y - z)^T
//   y[(s,j), i] = sum_k RM[s,j,k] * M[i,k];  z likewise with RP,P
//   out[s, i, j] = x[s,i,j] * (y - z)
__global__ __launch_bounds__(256, 2)
void k_pass2(const __hip_bfloat16* __restrict__ RM,
             const __hip_bfloat16* __restrict__ RP,
             const __hip_bfloat16* __restrict__ Mb,
             const __hip_bfloat16* __restrict__ Pb,
             const float* __restrict__ X,
             float* __restrict__ Out)
{
    __shared__ __hip_bfloat16 A1s[BM * BK];
    __shared__ __hip_bfloat16 A2s[BM * BK];
    __shared__ __hip_bfloat16 B1s[BN * BK];
    __shared__ __hip_bfloat16 B2s[BN * BK];
    const int t = threadIdx.x;
    const int l = t & 63, wv = t >> 6;
    const int m0 = blockIdx.y * BM, n0 = blockIdx.x * BN;
    const int col = l & 15, q = l >> 4;

    f32x4 accY[2][7], accZ[2][7];
    #pragma unroll
    for (int i = 0; i < 2; ++i)
        #pragma unroll
        for (int j = 0; j < 7; ++j) { accY[i][j] = (f32x4)0.f; accZ[i][j] = (f32x4)0.f; }

    for (int k0 = 0; k0 < Hdim; k0 += BK) {
        if (k0) __syncthreads();
        for (int i = wv; i < 8; i += 4) {      // A tiles: 8 insts each
            int r0 = i * 16;
            gl_lds16(RM + (size_t)(m0 + r0 + (l >> 2)) * Hdim + k0 + (l & 3) * 8,
                     &A1s[r0 * BK]);
            gl_lds16(RP + (size_t)(m0 + r0 + (l >> 2)) * Hdim + k0 + (l & 3) * 8,
                     &A2s[r0 * BK]);
        }
        for (int i = wv; i < 7; i += 4) {      // B tiles: 7 insts each
            int r0 = i * 16;
            gl_lds16(Mb + (size_t)(n0 + r0 + (l >> 2)) * Hdim + k0 + (l & 3) * 8,
                     &B1s[r0 * BK]);
            gl_lds16(Pb + (size_t)(n0 + r0 + (l >> 2)) * Hdim + k0 + (l & 3) * 8,
                     &B2s[r0 * BK]);
        }
        __syncthreads();
        const short8 a10 = *(const short8*)(&A1s[(wv * 32 + col) * BK + q * 8]);
        const short8 a11 = *(const short8*)(&A1s[(wv * 32 + 16 + col) * BK + q * 8]);
        const short8 a20 = *(const short8*)(&A2s[(wv * 32 + col) * BK + q * 8]);
        const short8 a21 = *(const short8*)(&A2s[(wv * 32 + 16 + col) * BK + q * 8]);
        #pragma unroll
        for (int j = 0; j < 7; ++j) {
            const short8 b1 = *(const short8*)(&B1s[(j * 16 + col) * BK + q * 8]);
            const short8 b2 = *(const short8*)(&B2s[(j * 16 + col) * BK + q * 8]);
            accY[0][j] = mfma_bf16(a10, b1, accY[0][j]);
            accY[1][j] = mfma_bf16(a11, b1, accY[1][j]);
            accZ[0][j] = mfma_bf16(a20, b2, accZ[0][j]);
            accZ[1][j] = mfma_bf16(a21, b2, accZ[1][j]);
        }
    }

    // epilogue: out[s, i, j0..j0+3] = x * (y - z); float4 in/out (16B aligned)
    #pragma unroll
    for (int i = 0; i < 2; ++i) {
        const int r0 = m0 + wv * 32 + i * 16 + q * 4;
        const int s = r0 / Hdim, jsp = r0 - (r0 / Hdim) * Hdim;
        #pragma unroll
        for (int j = 0; j < 7; ++j) {
            const int b = n0 + j * 16 + col;   // spatial i
            const size_t off = (size_t)s * HW + (size_t)b * Hdim + jsp;
            const float4 xv = *(const float4*)(X + off);
            float4 o;
            o.x = xv.x * (accY[i][j][0] - accZ[i][j][0]);
            o.y = xv.y * (accY[i][j][1] - accZ[i][j][1]);
            o.z = xv.z * (accY[i][j][2] - accZ[i][j][2]);
            o.w = xv.w * (accY[i][j][3] - accZ[i][j][3]);
            *(float4*)(Out + off) = o;
        }
    }
}

extern "C" void kernel_launch(void* const* d_in, const int* in_sizes, int n_in,
                              void* d_out, int out_size, void* d_ws, size_t ws_size,
                              hipStream_t stream) {
    const float* x = (const float*)d_in[0];
    float* out = (float*)d_out;
    float* w = (float*)d_ws;
    float* D = w + OFF_D;
    __hip_bfloat16* Mb = (__hip_bfloat16*)(w + OFF_M);
    __hip_bfloat16* Pb = (__hip_bfloat16*)(w + OFF_P);
    __hip_bfloat16* RM = (__hip_bfloat16*)(w + OFF_RM);
    __hip_bfloat16* RP = (__hip_bfloat16*)(w + OFF_RP);

    k_build_D<<<dim3((HW + 255) / 256), dim3(256), 0, stream>>>(D);
    k_build_MP<<<dim3((HW + 255) / 256), dim3(256), 0, stream>>>(D, Mb, Pb);

    dim3 grid(Hdim / BN, ROWS / BM);   // (2, 224) = 448 blocks
    dim3 blk(256);
    for (int c = 0; c < NCHUNK; ++c) {
        const float* xc = x + (size_t)c * CHUNK * HW;
        float* oc = out + (size_t)c * CHUNK * HW;
        k_pass1<<<grid, blk, 0, stream>>>(xc, Mb, Pb, RM, RP);
        k_pass2<<<grid, blk, 0, stream>>>(RM, RP, Mb, Pb, xc, oc);
    }
}